// Round 10
// baseline (500.532 us; speedup 1.0000x reference)
//
#include <hip/hip_runtime.h>
#include <hip/hip_bf16.h>

#define F 64
#define GRAPHS 512
#define CLASSES 10
#define SCAN_T 1024
#define NBLK 256       // histogram/scatter blocks (power of 2)
#define OUTCAP 8448    // bucket CSR slots (mean ~4350, sigma ~64 — never overflows)

typedef short bf16x8 __attribute__((ext_vector_type(8)));
typedef float f32x4 __attribute__((ext_vector_type(4)));
typedef float v2f __attribute__((ext_vector_type(2)));

// ---------------- fused: layer-1 MFMA GEMM (blocks 0..GB-1) + dst histogram (GB..GB+NBLK-1)
// + graph-bounds binary search (last 3 blocks). gemm and CSR-hist are independent; fusing
// hides the ~10us hist pass inside the gemm and drops one launch.
__global__ void gemm_hist(const float* __restrict__ x, const float* __restrict__ W,
                          const float* __restrict__ asrc, const float* __restrict__ adst,
                          unsigned* __restrict__ hb, float* __restrict__ es,
                          float* __restrict__ ed, int N, int GB,
                          const int* __restrict__ ei, int E, int NB,
                          int* __restrict__ hist,
                          const int* __restrict__ batch, int* __restrict__ gstart) {
    extern __shared__ unsigned lds[];
    int tid = threadIdx.x;

    if (blockIdx.x >= GB) {
        int blk = blockIdx.x - GB;
        if (blk < NBLK) {
            int* lh = (int*)lds;
            lh[tid] = 0; lh[tid + 256] = 0;
            __syncthreads();
            int chunk = (E + NBLK - 1) / NBLK;
            int b = blk * chunk, e = min(E, b + chunk);
            for (int i = b + tid; i < e; i += 256) atomicAdd(&lh[ei[E + i] >> 8], 1);
            __syncthreads();
            for (int j = tid; j < NB; j += 256) hist[j * NBLK + blk] = lh[j];
        } else {
            int g = (blk - NBLK) * 256 + tid;
            if (g > GRAPHS) return;
            int lo = 0, hi = N;
            while (lo < hi) {
                int mid = (lo + hi) >> 1;
                if (batch[mid] < g) lo = mid + 1; else hi = mid;
            }
            gstart[g] = lo;
        }
        return;
    }

    unsigned* Wf = lds;            // [2 planes][4 ks][4 kg][4 ct][16 col][4 jp] dwords = 8192
    unsigned* hs = lds + 8192;     // [64 rows][32] packed bf16-pair dwords = 2048
    {
        int col = tid & 15, ct = (tid >> 4) & 3, jp = tid >> 6;
        int c = 16 * ct + col;
        #pragma unroll
        for (int ks = 0; ks < 4; ++ks)
        #pragma unroll
        for (int kg = 0; kg < 4; ++kg) {
            int k0 = 32 * ks + 8 * kg + 2 * jp;
            float w0 = W[k0 * F + c];
            float w1 = W[(k0 + 1) * F + c];
            unsigned u0 = __float_as_uint(w0), u1 = __float_as_uint(w1);
            unsigned h0 = u0 & 0xFFFF0000u, h1 = u1 & 0xFFFF0000u;
            float l0 = w0 - __uint_as_float(h0);
            float l1 = w1 - __uint_as_float(h1);
            int base = (((ks * 4 + kg) * 4 + ct) * 16 + col) * 4 + jp;
            Wf[base] = h1 | (u0 >> 16);
            Wf[4096 + base] = (__float_as_uint(l1) & 0xFFFF0000u) | (__float_as_uint(l0) >> 16);
        }
    }
    __syncthreads();

    int wave = tid >> 6, lane = tid & 63;
    int kg = lane >> 4, r16 = lane & 15;
    int wbase = blockIdx.x * 64 + wave * 16;
    int row = wbase + r16;
    int rowc = min(row, N - 1);
    const float4* xrow = (const float4*)(x + (size_t)rowc * 128 + kg * 8);

    f32x4 acc0 = {0.f, 0.f, 0.f, 0.f}, acc1 = {0.f, 0.f, 0.f, 0.f};
    f32x4 acc2 = {0.f, 0.f, 0.f, 0.f}, acc3 = {0.f, 0.f, 0.f, 0.f};
    union U8 { uint4 u; bf16x8 h; };

    #pragma unroll
    for (int ks = 0; ks < 4; ++ks) {
        float4 q0 = xrow[8 * ks];
        float4 q1 = xrow[8 * ks + 1];
        U8 Ah, Al;
        {
            unsigned u0 = __float_as_uint(q0.x), u1 = __float_as_uint(q0.y);
            unsigned h0 = u0 & 0xFFFF0000u, h1 = u1 & 0xFFFF0000u;
            float l0 = q0.x - __uint_as_float(h0), l1 = q0.y - __uint_as_float(h1);
            Ah.u.x = h1 | (u0 >> 16);
            Al.u.x = (__float_as_uint(l1) & 0xFFFF0000u) | (__float_as_uint(l0) >> 16);
        }
        {
            unsigned u0 = __float_as_uint(q0.z), u1 = __float_as_uint(q0.w);
            unsigned h0 = u0 & 0xFFFF0000u, h1 = u1 & 0xFFFF0000u;
            float l0 = q0.z - __uint_as_float(h0), l1 = q0.w - __uint_as_float(h1);
            Ah.u.y = h1 | (u0 >> 16);
            Al.u.y = (__float_as_uint(l1) & 0xFFFF0000u) | (__float_as_uint(l0) >> 16);
        }
        {
            unsigned u0 = __float_as_uint(q1.x), u1 = __float_as_uint(q1.y);
            unsigned h0 = u0 & 0xFFFF0000u, h1 = u1 & 0xFFFF0000u;
            float l0 = q1.x - __uint_as_float(h0), l1 = q1.y - __uint_as_float(h1);
            Ah.u.z = h1 | (u0 >> 16);
            Al.u.z = (__float_as_uint(l1) & 0xFFFF0000u) | (__float_as_uint(l0) >> 16);
        }
        {
            unsigned u0 = __float_as_uint(q1.z), u1 = __float_as_uint(q1.w);
            unsigned h0 = u0 & 0xFFFF0000u, h1 = u1 & 0xFFFF0000u;
            float l0 = q1.z - __uint_as_float(h0), l1 = q1.w - __uint_as_float(h1);
            Ah.u.w = h1 | (u0 >> 16);
            Al.u.w = (__float_as_uint(l1) & 0xFFFF0000u) | (__float_as_uint(l0) >> 16);
        }
        bf16x8 ah = Ah.h, al = Al.h;
        #define CT_STEP(ct, ACC) { \
            int ad = (((ks * 4 + kg) * 4 + ct) * 16 + r16) * 4; \
            bf16x8 bh = *(const bf16x8*)&Wf[ad]; \
            bf16x8 bl = *(const bf16x8*)&Wf[4096 + ad]; \
            ACC = __builtin_amdgcn_mfma_f32_16x16x32_bf16(ah, bh, ACC, 0, 0, 0); \
            ACC = __builtin_amdgcn_mfma_f32_16x16x32_bf16(ah, bl, ACC, 0, 0, 0); \
            ACC = __builtin_amdgcn_mfma_f32_16x16x32_bf16(al, bh, ACC, 0, 0, 0); \
        }
        CT_STEP(0, acc0)
        CT_STEP(1, acc1)
        CT_STEP(2, acc2)
        CT_STEP(3, acc3)
        #undef CT_STEP
    }

    float as0 = asrc[r16], as1 = asrc[16 + r16], as2 = asrc[32 + r16], as3 = asrc[48 + r16];
    float ad0 = adst[r16], ad1 = adst[16 + r16], ad2 = adst[32 + r16], ad3 = adst[48 + r16];
    #pragma unroll
    for (int r = 0; r < 4; ++r) {
        float vs = acc0[r] * as0 + acc1[r] * as1 + acc2[r] * as2 + acc3[r] * as3;
        float vd = acc0[r] * ad0 + acc1[r] * ad1 + acc2[r] * ad2 + acc3[r] * ad3;
        #pragma unroll
        for (int o = 1; o <= 8; o <<= 1) {
            vs += __shfl_xor(vs, o);
            vd += __shfl_xor(vd, o);
        }
        int rr = wbase + kg * 4 + r;
        if (r16 == 0 && rr < N) { es[rr] = vs; ed[rr] = vd; }
    }
    #define PACK_CT(ct, ACC) { \
        _Pragma("unroll") \
        for (int r = 0; r < 4; ++r) { \
            unsigned ub = __float_as_uint(ACC[r]); \
            unsigned rb = (ub + 0x7FFF + ((ub >> 16) & 1)) >> 16; \
            unsigned pb = (unsigned)__shfl_xor((int)rb, 1); \
            if ((lane & 1) == 0) \
                hs[(wave * 16 + kg * 4 + r) * 32 + 8 * ct + (r16 >> 1)] = (pb << 16) | rb; \
        } \
    }
    PACK_CT(0, acc0)
    PACK_CT(1, acc1)
    PACK_CT(2, acc2)
    PACK_CT(3, acc3)
    #undef PACK_CT
    __syncthreads();
    int nrows = min(64, N - blockIdx.x * 64);
    unsigned* hbase = hb + (size_t)blockIdx.x * 64 * 32;
    for (int i = tid; i < nrows * 32; i += 256) hbase[i] = hs[i];
}

// ---------------- fused exclusive scan (partial + block scan + final in one kernel) ----------
__global__ void scan_all(const int* __restrict__ hist, int M, int* __restrict__ shist) {
    __shared__ int wsum[16];
    int t = threadIdx.x;
    int chunk = (M + SCAN_T - 1) / SCAN_T;
    int b = t * chunk, e = min(M, b + chunk);
    int s = 0;
    for (int l = b; l < e; ++l) s += hist[l];
    int lane = t & 63, w = t >> 6;
    int v = s;
    #pragma unroll
    for (int o = 1; o < 64; o <<= 1) {
        int u = __shfl_up(v, o);
        if (lane >= o) v += u;
    }
    if (lane == 63) wsum[w] = v;
    __syncthreads();
    if (t == 0) {
        int run = 0;
        for (int i = 0; i < 16; ++i) { int x2 = wsum[i]; wsum[i] = run; run += x2; }
    }
    __syncthreads();
    int run = v - s + wsum[w];   // exclusive prefix of this thread's chunk
    for (int l = b; l < e; ++l) {
        int h = hist[l];
        shist[l] = run;
        run += h;
    }
}

// ---------------- phase 3: binned scatter, LDS cursors only ----------------
__global__ void scatter3(const int* __restrict__ ei, int E, int NB,
                         const int* __restrict__ shist, unsigned* __restrict__ stage) {
    __shared__ int offs[512];
    int blk = blockIdx.x, tid = threadIdx.x;
    for (int j = tid; j < NB; j += 256) offs[j] = shist[j * NBLK + blk];
    __syncthreads();
    int chunk = (E + NBLK - 1) / NBLK;
    int b = blk * chunk, e = min(E, b + chunk);
    for (int i = b + tid; i < e; i += 256) {
        int s = ei[i], d = ei[E + i];
        int pos = atomicAdd(&offs[d >> 8], 1);
        stage[pos] = (unsigned)s | ((unsigned)(d & 255) << 24);
    }
}

// ---------------- phase 4: per-bucket place; derives rowptr; coalesced CSR flush ---------
__global__ void place2(const unsigned* __restrict__ stage, const int* __restrict__ shist,
                       int* __restrict__ rowptr, int* __restrict__ csr_src,
                       int N, int E, int NB) {
    __shared__ int cnt[256];
    __shared__ int cur[256];
    __shared__ int wsum[4];
    __shared__ int out[OUTCAP];
    int tid = threadIdx.x, bkt = blockIdx.x;
    int n0 = bkt << 8;
    int nn = min(256, N - n0);
    int eb = shist[bkt * NBLK];
    int ee = (bkt == NB - 1) ? E : shist[(bkt + 1) * NBLK];
    int elen = ee - eb;
    int cb = eb + n0;
    int csrlen = elen + nn;
    cnt[tid] = 0;
    __syncthreads();
    for (int i = tid; i < elen; i += 256) atomicAdd(&cnt[stage[eb + i] >> 24], 1);
    __syncthreads();
    int v = (tid < nn) ? cnt[tid] + 1 : 0;
    int lane = tid & 63, w = tid >> 6;
    int incl = v;
    #pragma unroll
    for (int o = 1; o < 64; o <<= 1) {
        int u = __shfl_up(incl, o);
        if (lane >= o) incl += u;
    }
    if (lane == 63) wsum[w] = incl;
    __syncthreads();
    if (tid == 0) {
        int run = 0;
        for (int i = 0; i < 4; ++i) { int t = wsum[i]; wsum[i] = run; run += t; }
    }
    __syncthreads();
    int excl = incl - v + wsum[w];
    cur[tid] = excl;
    if (tid < nn) rowptr[n0 + tid] = cb + excl;
    if (bkt == NB - 1 && tid == 0) rowptr[N] = E + N;
    __syncthreads();
    if (csrlen <= OUTCAP) {
        for (int i = tid; i < elen; i += 256) {
            unsigned wd = stage[eb + i];
            int p = atomicAdd(&cur[wd >> 24], 1);
            out[p] = (int)(wd & 0xFFFFFFu);
        }
        __syncthreads();
        if (tid < nn) out[cur[tid]] = n0 + tid;
        __syncthreads();
        for (int i = tid; i < csrlen; i += 256) csr_src[cb + i] = out[i];
    } else {
        for (int i = tid; i < elen; i += 256) {
            unsigned wd = stage[eb + i];
            int p = atomicAdd(&cur[wd >> 24], 1);
            csr_src[cb + p] = (int)(wd & 0xFFFFFFu);
        }
        __syncthreads();
        if (tid < nn) csr_src[cb + cur[tid]] = n0 + tid;
    }
}

// ---------------- aggregate: 256 threads, 8 nodes/block (half-wave = one node) ----
// Gather: 8-lane edge groups, dwordx4/lane (16B of 128B bf16 row), pk-FMA accum,
// 2-pair-deep software pipeline (sw rows padded to 96 slots, w=0 pad addr-safe).
// LDS TIME-SHARE: sw overlays Ws; Ws staged after the gather barrier ->
// 18.4KB/block -> 8 blocks/CU (32 waves). Mean-pool FUSED. h-out stored DIRECT.
// At the random-access service-rate roofline (FETCH ~90MB @ ~1.55TB/s) — do not touch.
template<bool FUSE>
__global__ __launch_bounds__(256) void
gat_agg_fused(const unsigned* __restrict__ hb_in, const float* __restrict__ es_in,
              const float* __restrict__ ed_in, const int* __restrict__ rowptr,
              const int* __restrict__ csr_src, const float* __restrict__ bias,
              const float* __restrict__ Wn, const float* __restrict__ ans,
              const float* __restrict__ and_,
              const int* __restrict__ batch, int segoff,
              float* __restrict__ pooled,
              unsigned* __restrict__ hb_out,
              float* __restrict__ es_out, float* __restrict__ ed_out, int N) {
    extern __shared__ float smem[];
    __shared__ int gsh[8];
    float* Ws = smem;                                        // [16 k4][64 col] f4 (FUSE, late)
    float2* sw = (float2*)smem;                              // [8][96] overlays Ws (early)
    float* xs = smem + (FUSE ? 4096 : 1536);                 // [8][64] output rows

    int wave = threadIdx.x >> 6, lane = threadIdx.x & 63;
    int hw = lane >> 5, sub = lane & 31;
    int base8 = blockIdx.x * 8;
    int nl = 2 * wave + hw;                // node-local 0..7
    int node = base8 + nl;
    int nrows = min(8, N - base8);

    if (threadIdx.x < 8 && base8 + threadIdx.x < N)
        gsh[threadIdx.x] = batch[base8 + threadIdx.x];

    if (node < N) {
        int beg = rowptr[node], end = rowptr[node + 1];
        int cnt = end - beg;
        float edn = ed_in[node];
        const char* hbp = (const char*)hb_in;
        if (cnt <= 64) {
            int s1 = 0, s2 = 0;
            float e1 = -1e30f, e2 = -1e30f;
            if (sub < cnt) {
                s1 = csr_src[beg + sub];
                float t = es_in[s1] + edn;
                e1 = t > 0.f ? t : 0.2f * t;
            }
            if (sub + 32 < cnt) {
                s2 = csr_src[beg + 32 + sub];
                float t = es_in[s2] + edn;
                e2 = t > 0.f ? t : 0.2f * t;
            }
            float m = fmaxf(e1, e2);
            #pragma unroll
            for (int o = 16; o > 0; o >>= 1) m = fmaxf(m, __shfl_xor(m, o));
            float w1 = (sub < cnt) ? __expf(e1 - m) : 0.f;
            float w2 = (sub + 32 < cnt) ? __expf(e2 - m) : 0.f;
            float den = w1 + w2;
            #pragma unroll
            for (int o = 16; o > 0; o >>= 1) den += __shfl_xor(den, o);
            float2* swrow = &sw[nl * 96];
            swrow[sub] = make_float2(__int_as_float(s1 << 7), w1);
            swrow[32 + sub] = make_float2(__int_as_float(s2 << 7), w2);
            swrow[64 + sub] = make_float2(0.f, 0.f);   // pad 64..95, addr-safe, w=0

            int g = sub >> 3;                 // edge group 0..3
            int j16 = (sub & 7) << 4;         // byte offset of this lane's 16B chunk
            int nit = (cnt + 3) >> 2;
            v2f A0 = {0.f, 0.f}, A1 = {0.f, 0.f}, A2 = {0.f, 0.f}, A3 = {0.f, 0.f};
            v2f B0 = {0.f, 0.f}, B1 = {0.f, 0.f}, B2 = {0.f, 0.f}, B3 = {0.f, 0.f};

            #define PF(PA, PB, QA, QB, base) { \
                PA = swrow[(base) + g]; PB = swrow[(base) + 4 + g]; \
                QA = *(const uint4*)(hbp + (__float_as_int(PA.x) + j16)); \
                QB = *(const uint4*)(hbp + (__float_as_int(PB.x) + j16)); }
            #define CONSUME(PA, PB, QA, QB) { \
                v2f wA = {PA.y, PA.y}; \
                v2f wB = {PB.y, PB.y}; \
                v2f vA0 = {__uint_as_float(QA.x << 16), __uint_as_float(QA.x & 0xFFFF0000u)}; \
                v2f vA1 = {__uint_as_float(QA.y << 16), __uint_as_float(QA.y & 0xFFFF0000u)}; \
                v2f vA2 = {__uint_as_float(QA.z << 16), __uint_as_float(QA.z & 0xFFFF0000u)}; \
                v2f vA3 = {__uint_as_float(QA.w << 16), __uint_as_float(QA.w & 0xFFFF0000u)}; \
                A0 = __builtin_elementwise_fma(wA, vA0, A0); \
                A1 = __builtin_elementwise_fma(wA, vA1, A1); \
                A2 = __builtin_elementwise_fma(wA, vA2, A2); \
                A3 = __builtin_elementwise_fma(wA, vA3, A3); \
                v2f vB0 = {__uint_as_float(QB.x << 16), __uint_as_float(QB.x & 0xFFFF0000u)}; \
                v2f vB1 = {__uint_as_float(QB.y << 16), __uint_as_float(QB.y & 0xFFFF0000u)}; \
                v2f vB2 = {__uint_as_float(QB.z << 16), __uint_as_float(QB.z & 0xFFFF0000u)}; \
                v2f vB3 = {__uint_as_float(QB.w << 16), __uint_as_float(QB.w & 0xFFFF0000u)}; \
                B0 = __builtin_elementwise_fma(wB, vB0, B0); \
                B1 = __builtin_elementwise_fma(wB, vB1, B1); \
                B2 = __builtin_elementwise_fma(wB, vB2, B2); \
                B3 = __builtin_elementwise_fma(wB, vB3, B3); }

            float2 pA0, pB0, pA1, pB1, pA2, pB2;
            uint4 qA0, qB0, qA1, qB1, qA2, qB2;
            PF(pA0, pB0, qA0, qB0, 0)      // pair@0 (quads 0,1)
            PF(pA1, pB1, qA1, qB1, 8)      // pair@2 (quads 2,3)
            int i = 0;
            for (;;) {
                PF(pA2, pB2, qA2, qB2, 4 * i + 16)   // pair@(i+4)
                CONSUME(pA0, pB0, qA0, qB0)           // pair@i
                i += 2; if (i >= nit) break;
                PF(pA0, pB0, qA0, qB0, 4 * i + 16)
                CONSUME(pA1, pB1, qA1, qB1)
                i += 2; if (i >= nit) break;
                PF(pA1, pB1, qA1, qB1, 4 * i + 16)
                CONSUME(pA2, pB2, qA2, qB2)
                i += 2; if (i >= nit) break;
            }
            #undef PF
            #undef CONSUME

            A0 += B0; A1 += B1; A2 += B2; A3 += B3;
            float a0 = A0.x, a1 = A0.y, a2 = A1.x, a3 = A1.y;
            float a4 = A2.x, a5 = A2.y, a6 = A3.x, a7 = A3.y;
            #pragma unroll
            for (int o = 8; o <= 16; o <<= 1) {
                a0 += __shfl_xor(a0, o);
                a1 += __shfl_xor(a1, o);
                a2 += __shfl_xor(a2, o);
                a3 += __shfl_xor(a3, o);
                a4 += __shfl_xor(a4, o);
                a5 += __shfl_xor(a5, o);
                a6 += __shfl_xor(a6, o);
                a7 += __shfl_xor(a7, o);
            }
            float inv = 1.0f / (den + 1e-16f);
            if (sub < 16) {
                int jj = sub & 7;
                int half2 = sub >> 3;         // 0: feats 8jj+0..3, 1: feats 8jj+4..7
                float4 bv = ((const float4*)bias)[(jj << 1) | half2];
                float4 r;
                r.x = (half2 ? a4 : a0) * inv + bv.x;
                r.y = (half2 ? a5 : a1) * inv + bv.y;
                r.z = (half2 ? a6 : a2) * inv + bv.z;
                r.w = (half2 ? a7 : a3) * inv + bv.w;
                r.x = fmaxf(r.x, 0.f); r.y = fmaxf(r.y, 0.f);
                r.z = fmaxf(r.z, 0.f); r.w = fmaxf(r.w, 0.f);
                *(float4*)&xs[nl * 64 + jj * 8 + half2 * 4] = r;
            }
        } else {
            // slow path (deg>64, ~1e-18 prob): half-wave strided max, serial accumulate
            float m = -1e30f;
            for (int j = beg + sub; j < end; j += 32) {
                float e = es_in[csr_src[j]] + edn;
                e = e > 0.f ? e : 0.2f * e;
                m = fmaxf(m, e);
            }
            #pragma unroll
            for (int o = 16; o > 0; o >>= 1) m = fmaxf(m, __shfl_xor(m, o));
            float accL = 0.f, accH = 0.f, den = 0.f;
            for (int j = beg; j < end; ++j) {
                int s = csr_src[j];
                float e = es_in[s] + edn;
                e = e > 0.f ? e : 0.2f * e;
                float w = __expf(e - m);
                den += w;
                unsigned q = hb_in[(size_t)s * 32 + sub];
                accL = fmaf(w, __uint_as_float(q << 16), accL);
                accH = fmaf(w, __uint_as_float(q & 0xFFFF0000u), accH);
            }
            float inv = 1.0f / (den + 1e-16f);
            float2 b2v = ((const float2*)bias)[sub];
            float vL = accL * inv + b2v.x;
            float vH = accH * inv + b2v.y;
            vL = vL > 0.f ? vL : 0.f;
            vH = vH > 0.f ? vH : 0.f;
            ((float2*)&xs[nl * 64])[sub] = make_float2(vL, vH);
        }
    }
    __syncthreads();   // gather done: sw dead everywhere, xs complete

    // stage Ws over sw's region (FUSE only) — consumed after the next barrier
    if (FUSE) {
        int c = threadIdx.x & 63;
        int q0 = threadIdx.x >> 6;
        #pragma unroll
        for (int it = 0; it < 4; ++it) {
            int q = q0 + 4 * it;
            float4 v;
            v.x = Wn[(4 * q + 0) * F + c];
            v.y = Wn[(4 * q + 1) * F + c];
            v.z = Wn[(4 * q + 2) * F + c];
            v.w = Wn[(4 * q + 3) * F + c];
            *(float4*)&Ws[(q * 64 + c) * 4] = v;
        }
    }

    // fused mean-pool accumulation: wave 0, one feature per lane, run-reduce by graph
    if (threadIdx.x < 64) {
        int f = threadIdx.x;
        float s = 0.f;
        int gprev = gsh[0];
        for (int r = 0; r < nrows; ++r) {
            int g = gsh[r];
            if (g != gprev) {
                atomicAdd(&pooled[(size_t)gprev * 192 + segoff + f], s);
                s = 0.f; gprev = g;
            }
            s += xs[r * 64 + f];
        }
        atomicAdd(&pooled[(size_t)gprev * 192 + segoff + f], s);
    }

    if (FUSE) {
        __syncthreads();   // Ws visible to all waves
        float as_l = ans[lane];
        float ad_l = and_[lane];
        int r0 = wave, r1 = wave + 4;
        const float4* wv4 = (const float4*)Ws;
        const float4* x0v = (const float4*)&xs[r0 * 64];
        const float4* x1v = (const float4*)&xs[r1 * 64];
        float a0 = 0.f, a1 = 0.f, a2 = 0.f, a3 = 0.f;
        float b0 = 0.f, b1 = 0.f, b2 = 0.f, b3 = 0.f;
        #pragma unroll
        for (int k4 = 0; k4 < 16; ++k4) {
            float4 wv = wv4[k4 * 64 + lane];
            float4 xa = x0v[k4];
            float4 xb = x1v[k4];
            a0 = fmaf(xa.x, wv.x, a0);
            a1 = fmaf(xa.y, wv.y, a1);
            a2 = fmaf(xa.z, wv.z, a2);
            a3 = fmaf(xa.w, wv.w, a3);
            b0 = fmaf(xb.x, wv.x, b0);
            b1 = fmaf(xb.y, wv.y, b1);
            b2 = fmaf(xb.z, wv.z, b2);
            b3 = fmaf(xb.w, wv.w, b3);
        }
        float h0 = (a0 + a1) + (a2 + a3);
        float h1 = (b0 + b1) + (b2 + b3);
        float vs0 = h0 * as_l, vd0 = h0 * ad_l;
        float vs1 = h1 * as_l, vd1 = h1 * ad_l;
        #pragma unroll
        for (int o = 32; o > 0; o >>= 1) {
            vs0 += __shfl_down(vs0, o);
            vd0 += __shfl_down(vd0, o);
            vs1 += __shfl_down(vs1, o);
            vd1 += __shfl_down(vd1, o);
        }
        int nd0 = base8 + r0, nd1 = base8 + r1;
        if (lane == 0) {
            if (nd0 < N) { es_out[nd0] = vs0; ed_out[nd0] = vd0; }
            if (nd1 < N) { es_out[nd1] = vs1; ed_out[nd1] = vd1; }
        }
        unsigned u0 = __float_as_uint(h0);
        unsigned rb0 = (u0 + 0x7FFF + ((u0 >> 16) & 1)) >> 16;
        unsigned pb0 = (unsigned)__shfl_xor((int)rb0, 1);
        unsigned u1 = __float_as_uint(h1);
        unsigned rb1 = (u1 + 0x7FFF + ((u1 >> 16) & 1)) >> 16;
        unsigned pb1 = (unsigned)__shfl_xor((int)rb1, 1);
        if ((lane & 1) == 0) {
            if (nd0 < N) hb_out[(size_t)nd0 * 32 + (lane >> 1)] = (pb0 << 16) | rb0;
            if (nd1 < N) hb_out[(size_t)nd1 * 32 + (lane >> 1)] = (pb1 << 16) | rb1;
        }
    }
}

// ---------------- final linear + softmax ----------------
__global__ void head_kernel(const float* __restrict__ pooled, const int* __restrict__ gstart,
                            const float* __restrict__ Wo, const float* __restrict__ bo,
                            float* __restrict__ out) {
    int g = blockIdx.x * blockDim.x + threadIdx.x;
    if (g >= GRAPHS) return;
    int cntg = gstart[g + 1] - gstart[g];
    float inv = 1.0f / fmaxf((float)cntg, 1.0f);
    float acc[CLASSES];
    #pragma unroll
    for (int c = 0; c < CLASSES; ++c) acc[c] = bo[c];
    for (int f = 0; f < 192; ++f) {
        float p = pooled[g * 192 + f] * inv;
        #pragma unroll
        for (int c = 0; c < CLASSES; ++c) acc[c] = fmaf(p, Wo[f * CLASSES + c], acc[c]);
    }
    float mx = acc[0];
    #pragma unroll
    for (int c = 1; c < CLASSES; ++c) mx = fmaxf(mx, acc[c]);
    float s = 0.f;
    #pragma unroll
    for (int c = 0; c < CLASSES; ++c) { acc[c] = __expf(acc[c] - mx); s += acc[c]; }
    float invs = 1.0f / s;
    #pragma unroll
    for (int c = 0; c < CLASSES; ++c) out[g * CLASSES + c] = acc[c] * invs;
}

extern "C" void kernel_launch(void* const* d_in, const int* in_sizes, int n_in,
                              void* d_out, int out_size, void* d_ws, size_t ws_size,
                              hipStream_t stream) {
    const float* x   = (const float*)d_in[0];
    const int* ei    = (const int*)d_in[1];
    const int* batch = (const int*)d_in[2];
    const float* W1  = (const float*)d_in[3];
    const float* a1s = (const float*)d_in[4];
    const float* a1d = (const float*)d_in[5];
    const float* b1  = (const float*)d_in[6];
    const float* W2  = (const float*)d_in[7];
    const float* a2s = (const float*)d_in[8];
    const float* a2d = (const float*)d_in[9];
    const float* b2  = (const float*)d_in[10];
    const float* W3  = (const float*)d_in[11];
    const float* a3s = (const float*)d_in[12];
    const float* a3d = (const float*)d_in[13];
    const float* b3  = (const float*)d_in[14];
    const float* Wo  = (const float*)d_in[15];
    const float* bo  = (const float*)d_in[16];
    float* out = (float*)d_out;

    const int N = in_sizes[2];
    const int E = in_sizes[1] / 2;
    const int TOT = E + N;
    const int NB = (N + 255) >> 8;
    const int M  = NB * NBLK;

    char* p = (char*)d_ws;
    auto alloc = [&](size_t bytes) { char* r = p; p += (bytes + 255) & ~(size_t)255; return r; };
    unsigned* hbA  = (unsigned*)alloc((size_t)N * 32 * 4);
    unsigned* hbB  = (unsigned*)alloc((size_t)N * 32 * 4);
    float* esA     = (float*)alloc((size_t)N * 4);
    float* edA     = (float*)alloc((size_t)N * 4);
    float* esB     = (float*)alloc((size_t)N * 4);
    float* edB     = (float*)alloc((size_t)N * 4);
    int* rowptr    = (int*)alloc((size_t)(N + 1) * 4);
    int* csr_src   = (int*)alloc((size_t)TOT * 4);
    unsigned* stage= (unsigned*)alloc((size_t)E * 4);
    int* hist      = (int*)alloc((size_t)M * 4);
    int* shist     = (int*)alloc((size_t)M * 4);
    float* pooled  = (float*)alloc((size_t)GRAPHS * 192 * 4);
    int* gstart    = (int*)alloc((size_t)(GRAPHS + 1) * 4);

    hipMemsetAsync(pooled, 0, (size_t)GRAPHS * 192 * 4, stream);

    const int GB = (N + 63) / 64;
    const size_t SMG = 40960;                                  // Wf (32KB) + hs (8KB)
    const size_t SMF  = (size_t)4096 * 4 + 2048;               // Ws(=sw overlay 16K) + xs = 18.4KB
    const size_t SMNF = 6144 + 2048;                           // sw(8x96) + xs
    int agg_blocks = (N + 7) / 8;

    // fused layer-1 GEMM + dst-histogram + graph-bounds (independent work, one launch)
    gemm_hist<<<GB + NBLK + 3, 256, SMG, stream>>>(x, W1, a1s, a1d, hbA, esA, edA, N, GB,
                                                   ei, E, NB, hist, batch, gstart);
    // fused exclusive scan (was 3 kernels)
    scan_all<<<1, SCAN_T, 0, stream>>>(hist, M, shist);
    scatter3<<<NBLK, 256, 0, stream>>>(ei, E, NB, shist, stage);
    place2<<<NB, 256, 0, stream>>>(stage, shist, rowptr, csr_src, N, E, NB);

    // agg1 (+pool seg0) + fused gemm2
    gat_agg_fused<true><<<agg_blocks, 256, SMF, stream>>>(hbA, esA, edA, rowptr, csr_src, b1,
                                                          W2, a2s, a2d, batch, 0, pooled,
                                                          hbB, esB, edB, N);
    // agg2 (+pool seg1) + fused gemm3
    gat_agg_fused<true><<<agg_blocks, 256, SMF, stream>>>(hbB, esB, edB, rowptr, csr_src, b2,
                                                          W3, a3s, a3d, batch, 64, pooled,
                                                          hbA, esA, edA, N);
    // agg3 (+pool seg2, no fusion)
    gat_agg_fused<false><<<agg_blocks, 256, SMNF, stream>>>(hbA, esA, edA, rowptr, csr_src, b3,
                                                            nullptr, nullptr, nullptr,
                                                            batch, 128, pooled,
                                                            nullptr, nullptr, nullptr, N);

    // readout
    head_kernel<<<(GRAPHS + 255) / 256, 256, 0, stream>>>(pooled, gstart, Wo, bo, out);
}

// Round 11
// 348.493 us; speedup vs baseline: 1.4363x; 1.4363x over previous
//
#include <hip/hip_runtime.h>
#include <hip/hip_bf16.h>

#define F 64
#define GRAPHS 512
#define CLASSES 10
#define SCAN_T 1024
#define NBLK 256       // histogram/scatter blocks (power of 2)
#define OUTCAP 8448    // bucket CSR slots (mean ~4350, sigma ~64 — never overflows)

typedef short bf16x8 __attribute__((ext_vector_type(8)));
typedef float f32x4 __attribute__((ext_vector_type(4)));
typedef float v2f __attribute__((ext_vector_type(2)));

// ---------------- fused: layer-1 MFMA GEMM (blocks 0..GB-1) + dst histogram (GB..GB+NBLK-1)
// + graph-bounds binary search (last 3 blocks). gemm and CSR-hist are independent; fusing
// hides the ~10us hist pass inside the gemm and drops one launch.
__global__ void gemm_hist(const float* __restrict__ x, const float* __restrict__ W,
                          const float* __restrict__ asrc, const float* __restrict__ adst,
                          unsigned* __restrict__ hb, float* __restrict__ es,
                          float* __restrict__ ed, int N, int GB,
                          const int* __restrict__ ei, int E, int NB,
                          int* __restrict__ hist,
                          const int* __restrict__ batch, int* __restrict__ gstart) {
    extern __shared__ unsigned lds[];
    int tid = threadIdx.x;

    if (blockIdx.x >= GB) {
        int blk = blockIdx.x - GB;
        if (blk < NBLK) {
            int* lh = (int*)lds;
            lh[tid] = 0; lh[tid + 256] = 0;
            __syncthreads();
            int chunk = (E + NBLK - 1) / NBLK;
            int b = blk * chunk, e = min(E, b + chunk);
            for (int i = b + tid; i < e; i += 256) atomicAdd(&lh[ei[E + i] >> 8], 1);
            __syncthreads();
            for (int j = tid; j < NB; j += 256) hist[j * NBLK + blk] = lh[j];
        } else {
            int g = (blk - NBLK) * 256 + tid;
            if (g > GRAPHS) return;
            int lo = 0, hi = N;
            while (lo < hi) {
                int mid = (lo + hi) >> 1;
                if (batch[mid] < g) lo = mid + 1; else hi = mid;
            }
            gstart[g] = lo;
        }
        return;
    }

    unsigned* Wf = lds;            // [2 planes][4 ks][4 kg][4 ct][16 col][4 jp] dwords = 8192
    unsigned* hs = lds + 8192;     // [64 rows][32] packed bf16-pair dwords = 2048
    {
        int col = tid & 15, ct = (tid >> 4) & 3, jp = tid >> 6;
        int c = 16 * ct + col;
        #pragma unroll
        for (int ks = 0; ks < 4; ++ks)
        #pragma unroll
        for (int kg = 0; kg < 4; ++kg) {
            int k0 = 32 * ks + 8 * kg + 2 * jp;
            float w0 = W[k0 * F + c];
            float w1 = W[(k0 + 1) * F + c];
            unsigned u0 = __float_as_uint(w0), u1 = __float_as_uint(w1);
            unsigned h0 = u0 & 0xFFFF0000u, h1 = u1 & 0xFFFF0000u;
            float l0 = w0 - __uint_as_float(h0);
            float l1 = w1 - __uint_as_float(h1);
            int base = (((ks * 4 + kg) * 4 + ct) * 16 + col) * 4 + jp;
            Wf[base] = h1 | (u0 >> 16);
            Wf[4096 + base] = (__float_as_uint(l1) & 0xFFFF0000u) | (__float_as_uint(l0) >> 16);
        }
    }
    __syncthreads();

    int wave = tid >> 6, lane = tid & 63;
    int kg = lane >> 4, r16 = lane & 15;
    int wbase = blockIdx.x * 64 + wave * 16;
    int row = wbase + r16;
    int rowc = min(row, N - 1);
    const float4* xrow = (const float4*)(x + (size_t)rowc * 128 + kg * 8);

    f32x4 acc0 = {0.f, 0.f, 0.f, 0.f}, acc1 = {0.f, 0.f, 0.f, 0.f};
    f32x4 acc2 = {0.f, 0.f, 0.f, 0.f}, acc3 = {0.f, 0.f, 0.f, 0.f};
    union U8 { uint4 u; bf16x8 h; };

    #pragma unroll
    for (int ks = 0; ks < 4; ++ks) {
        float4 q0 = xrow[8 * ks];
        float4 q1 = xrow[8 * ks + 1];
        U8 Ah, Al;
        {
            unsigned u0 = __float_as_uint(q0.x), u1 = __float_as_uint(q0.y);
            unsigned h0 = u0 & 0xFFFF0000u, h1 = u1 & 0xFFFF0000u;
            float l0 = q0.x - __uint_as_float(h0), l1 = q0.y - __uint_as_float(h1);
            Ah.u.x = h1 | (u0 >> 16);
            Al.u.x = (__float_as_uint(l1) & 0xFFFF0000u) | (__float_as_uint(l0) >> 16);
        }
        {
            unsigned u0 = __float_as_uint(q0.z), u1 = __float_as_uint(q0.w);
            unsigned h0 = u0 & 0xFFFF0000u, h1 = u1 & 0xFFFF0000u;
            float l0 = q0.z - __uint_as_float(h0), l1 = q0.w - __uint_as_float(h1);
            Ah.u.y = h1 | (u0 >> 16);
            Al.u.y = (__float_as_uint(l1) & 0xFFFF0000u) | (__float_as_uint(l0) >> 16);
        }
        {
            unsigned u0 = __float_as_uint(q1.x), u1 = __float_as_uint(q1.y);
            unsigned h0 = u0 & 0xFFFF0000u, h1 = u1 & 0xFFFF0000u;
            float l0 = q1.x - __uint_as_float(h0), l1 = q1.y - __uint_as_float(h1);
            Ah.u.z = h1 | (u0 >> 16);
            Al.u.z = (__float_as_uint(l1) & 0xFFFF0000u) | (__float_as_uint(l0) >> 16);
        }
        {
            unsigned u0 = __float_as_uint(q1.z), u1 = __float_as_uint(q1.w);
            unsigned h0 = u0 & 0xFFFF0000u, h1 = u1 & 0xFFFF0000u;
            float l0 = q1.z - __uint_as_float(h0), l1 = q1.w - __uint_as_float(h1);
            Ah.u.w = h1 | (u0 >> 16);
            Al.u.w = (__float_as_uint(l1) & 0xFFFF0000u) | (__float_as_uint(l0) >> 16);
        }
        bf16x8 ah = Ah.h, al = Al.h;
        #define CT_STEP(ct, ACC) { \
            int ad = (((ks * 4 + kg) * 4 + ct) * 16 + r16) * 4; \
            bf16x8 bh = *(const bf16x8*)&Wf[ad]; \
            bf16x8 bl = *(const bf16x8*)&Wf[4096 + ad]; \
            ACC = __builtin_amdgcn_mfma_f32_16x16x32_bf16(ah, bh, ACC, 0, 0, 0); \
            ACC = __builtin_amdgcn_mfma_f32_16x16x32_bf16(ah, bl, ACC, 0, 0, 0); \
            ACC = __builtin_amdgcn_mfma_f32_16x16x32_bf16(al, bh, ACC, 0, 0, 0); \
        }
        CT_STEP(0, acc0)
        CT_STEP(1, acc1)
        CT_STEP(2, acc2)
        CT_STEP(3, acc3)
        #undef CT_STEP
    }

    float as0 = asrc[r16], as1 = asrc[16 + r16], as2 = asrc[32 + r16], as3 = asrc[48 + r16];
    float ad0 = adst[r16], ad1 = adst[16 + r16], ad2 = adst[32 + r16], ad3 = adst[48 + r16];
    #pragma unroll
    for (int r = 0; r < 4; ++r) {
        float vs = acc0[r] * as0 + acc1[r] * as1 + acc2[r] * as2 + acc3[r] * as3;
        float vd = acc0[r] * ad0 + acc1[r] * ad1 + acc2[r] * ad2 + acc3[r] * ad3;
        #pragma unroll
        for (int o = 1; o <= 8; o <<= 1) {
            vs += __shfl_xor(vs, o);
            vd += __shfl_xor(vd, o);
        }
        int rr = wbase + kg * 4 + r;
        if (r16 == 0 && rr < N) { es[rr] = vs; ed[rr] = vd; }
    }
    #define PACK_CT(ct, ACC) { \
        _Pragma("unroll") \
        for (int r = 0; r < 4; ++r) { \
            unsigned ub = __float_as_uint(ACC[r]); \
            unsigned rb = (ub + 0x7FFF + ((ub >> 16) & 1)) >> 16; \
            unsigned pb = (unsigned)__shfl_xor((int)rb, 1); \
            if ((lane & 1) == 0) \
                hs[(wave * 16 + kg * 4 + r) * 32 + 8 * ct + (r16 >> 1)] = (pb << 16) | rb; \
        } \
    }
    PACK_CT(0, acc0)
    PACK_CT(1, acc1)
    PACK_CT(2, acc2)
    PACK_CT(3, acc3)
    #undef PACK_CT
    __syncthreads();
    int nrows = min(64, N - blockIdx.x * 64);
    unsigned* hbase = hb + (size_t)blockIdx.x * 64 * 32;
    for (int i = tid; i < nrows * 32; i += 256) hbase[i] = hs[i];
}

// ---------------- parallel 3-phase exclusive scan over hist[M], M = NB*256 ----------------
// p1: one block per 256-elem tile, wave-reduce -> partial[b]
__global__ void scan_p1(const int* __restrict__ hist, int* __restrict__ partial) {
    __shared__ int ws[4];
    int t = threadIdx.x;
    int v = hist[blockIdx.x * 256 + t];
    int lane = t & 63, w = t >> 6;
    #pragma unroll
    for (int o = 1; o < 64; o <<= 1) v += __shfl_xor(v, o);
    if (lane == 0) ws[w] = v;
    __syncthreads();
    if (t == 0) partial[blockIdx.x] = ws[0] + ws[1] + ws[2] + ws[3];
}

// p2: single block scans up to 1024 block sums (exclusive, in place)
__global__ void scan_p2(int* __restrict__ partial, int nblk) {
    __shared__ int wsum[16];
    int t = threadIdx.x;
    int orig = (t < nblk) ? partial[t] : 0;
    int lane = t & 63, w = t >> 6;
    int v = orig;
    #pragma unroll
    for (int o = 1; o < 64; o <<= 1) {
        int u = __shfl_up(v, o);
        if (lane >= o) v += u;
    }
    if (lane == 63) wsum[w] = v;
    __syncthreads();
    if (t == 0) {
        int run = 0;
        for (int i = 0; i < 16; ++i) { int x2 = wsum[i]; wsum[i] = run; run += x2; }
    }
    __syncthreads();
    v += wsum[w];
    if (t < nblk) partial[t] = v - orig;
}

// p3: block-local exclusive scan of 256-elem tile + block offset -> shist
__global__ void scan_p3(const int* __restrict__ hist, const int* __restrict__ partial,
                        int* __restrict__ shist) {
    __shared__ int wsum[4];
    int t = threadIdx.x;
    int idx = blockIdx.x * 256 + t;
    int orig = hist[idx];
    int lane = t & 63, w = t >> 6;
    int v = orig;
    #pragma unroll
    for (int o = 1; o < 64; o <<= 1) {
        int u = __shfl_up(v, o);
        if (lane >= o) v += u;
    }
    if (lane == 63) wsum[w] = v;
    __syncthreads();
    if (t == 0) {
        int run = 0;
        for (int i = 0; i < 4; ++i) { int x2 = wsum[i]; wsum[i] = run; run += x2; }
    }
    __syncthreads();
    shist[idx] = v - orig + wsum[w] + partial[blockIdx.x];
}

// ---------------- phase 3: binned scatter, LDS cursors only ----------------
__global__ void scatter3(const int* __restrict__ ei, int E, int NB,
                         const int* __restrict__ shist, unsigned* __restrict__ stage) {
    __shared__ int offs[512];
    int blk = blockIdx.x, tid = threadIdx.x;
    for (int j = tid; j < NB; j += 256) offs[j] = shist[j * NBLK + blk];
    __syncthreads();
    int chunk = (E + NBLK - 1) / NBLK;
    int b = blk * chunk, e = min(E, b + chunk);
    for (int i = b + tid; i < e; i += 256) {
        int s = ei[i], d = ei[E + i];
        int pos = atomicAdd(&offs[d >> 8], 1);
        stage[pos] = (unsigned)s | ((unsigned)(d & 255) << 24);
    }
}

// ---------------- phase 4: per-bucket place; derives rowptr; coalesced CSR flush ---------
__global__ void place2(const unsigned* __restrict__ stage, const int* __restrict__ shist,
                       int* __restrict__ rowptr, int* __restrict__ csr_src,
                       int N, int E, int NB) {
    __shared__ int cnt[256];
    __shared__ int cur[256];
    __shared__ int wsum[4];
    __shared__ int out[OUTCAP];
    int tid = threadIdx.x, bkt = blockIdx.x;
    int n0 = bkt << 8;
    int nn = min(256, N - n0);
    int eb = shist[bkt * NBLK];
    int ee = (bkt == NB - 1) ? E : shist[(bkt + 1) * NBLK];
    int elen = ee - eb;
    int cb = eb + n0;
    int csrlen = elen + nn;
    cnt[tid] = 0;
    __syncthreads();
    for (int i = tid; i < elen; i += 256) atomicAdd(&cnt[stage[eb + i] >> 24], 1);
    __syncthreads();
    int v = (tid < nn) ? cnt[tid] + 1 : 0;
    int lane = tid & 63, w = tid >> 6;
    int incl = v;
    #pragma unroll
    for (int o = 1; o < 64; o <<= 1) {
        int u = __shfl_up(incl, o);
        if (lane >= o) incl += u;
    }
    if (lane == 63) wsum[w] = incl;
    __syncthreads();
    if (tid == 0) {
        int run = 0;
        for (int i = 0; i < 4; ++i) { int t = wsum[i]; wsum[i] = run; run += t; }
    }
    __syncthreads();
    int excl = incl - v + wsum[w];
    cur[tid] = excl;
    if (tid < nn) rowptr[n0 + tid] = cb + excl;
    if (bkt == NB - 1 && tid == 0) rowptr[N] = E + N;
    __syncthreads();
    if (csrlen <= OUTCAP) {
        for (int i = tid; i < elen; i += 256) {
            unsigned wd = stage[eb + i];
            int p = atomicAdd(&cur[wd >> 24], 1);
            out[p] = (int)(wd & 0xFFFFFFu);
        }
        __syncthreads();
        if (tid < nn) out[cur[tid]] = n0 + tid;
        __syncthreads();
        for (int i = tid; i < csrlen; i += 256) csr_src[cb + i] = out[i];
    } else {
        for (int i = tid; i < elen; i += 256) {
            unsigned wd = stage[eb + i];
            int p = atomicAdd(&cur[wd >> 24], 1);
            csr_src[cb + p] = (int)(wd & 0xFFFFFFu);
        }
        __syncthreads();
        if (tid < nn) csr_src[cb + cur[tid]] = n0 + tid;
    }
}

// ---------------- aggregate: 256 threads, 8 nodes/block (half-wave = one node) ----
// Gather: 8-lane edge groups, dwordx4/lane (16B of 128B bf16 row), pk-FMA accum,
// 2-pair-deep software pipeline (sw rows padded to 96 slots, w=0 pad addr-safe).
// LDS TIME-SHARE: sw overlays Ws; Ws staged after the gather barrier ->
// 18.4KB/block -> 8 blocks/CU (32 waves). Mean-pool FUSED. h-out stored DIRECT.
// At the random-access service-rate roofline (FETCH ~90MB @ ~1.55TB/s) — do not touch.
template<bool FUSE>
__global__ __launch_bounds__(256) void
gat_agg_fused(const unsigned* __restrict__ hb_in, const float* __restrict__ es_in,
              const float* __restrict__ ed_in, const int* __restrict__ rowptr,
              const int* __restrict__ csr_src, const float* __restrict__ bias,
              const float* __restrict__ Wn, const float* __restrict__ ans,
              const float* __restrict__ and_,
              const int* __restrict__ batch, int segoff,
              float* __restrict__ pooled,
              unsigned* __restrict__ hb_out,
              float* __restrict__ es_out, float* __restrict__ ed_out, int N) {
    extern __shared__ float smem[];
    __shared__ int gsh[8];
    float* Ws = smem;                                        // [16 k4][64 col] f4 (FUSE, late)
    float2* sw = (float2*)smem;                              // [8][96] overlays Ws (early)
    float* xs = smem + (FUSE ? 4096 : 1536);                 // [8][64] output rows

    int wave = threadIdx.x >> 6, lane = threadIdx.x & 63;
    int hw = lane >> 5, sub = lane & 31;
    int base8 = blockIdx.x * 8;
    int nl = 2 * wave + hw;                // node-local 0..7
    int node = base8 + nl;
    int nrows = min(8, N - base8);

    if (threadIdx.x < 8 && base8 + threadIdx.x < N)
        gsh[threadIdx.x] = batch[base8 + threadIdx.x];

    if (node < N) {
        int beg = rowptr[node], end = rowptr[node + 1];
        int cnt = end - beg;
        float edn = ed_in[node];
        const char* hbp = (const char*)hb_in;
        if (cnt <= 64) {
            int s1 = 0, s2 = 0;
            float e1 = -1e30f, e2 = -1e30f;
            if (sub < cnt) {
                s1 = csr_src[beg + sub];
                float t = es_in[s1] + edn;
                e1 = t > 0.f ? t : 0.2f * t;
            }
            if (sub + 32 < cnt) {
                s2 = csr_src[beg + 32 + sub];
                float t = es_in[s2] + edn;
                e2 = t > 0.f ? t : 0.2f * t;
            }
            float m = fmaxf(e1, e2);
            #pragma unroll
            for (int o = 16; o > 0; o >>= 1) m = fmaxf(m, __shfl_xor(m, o));
            float w1 = (sub < cnt) ? __expf(e1 - m) : 0.f;
            float w2 = (sub + 32 < cnt) ? __expf(e2 - m) : 0.f;
            float den = w1 + w2;
            #pragma unroll
            for (int o = 16; o > 0; o >>= 1) den += __shfl_xor(den, o);
            float2* swrow = &sw[nl * 96];
            swrow[sub] = make_float2(__int_as_float(s1 << 7), w1);
            swrow[32 + sub] = make_float2(__int_as_float(s2 << 7), w2);
            swrow[64 + sub] = make_float2(0.f, 0.f);   // pad 64..95, addr-safe, w=0

            int g = sub >> 3;                 // edge group 0..3
            int j16 = (sub & 7) << 4;         // byte offset of this lane's 16B chunk
            int nit = (cnt + 3) >> 2;
            v2f A0 = {0.f, 0.f}, A1 = {0.f, 0.f}, A2 = {0.f, 0.f}, A3 = {0.f, 0.f};
            v2f B0 = {0.f, 0.f}, B1 = {0.f, 0.f}, B2 = {0.f, 0.f}, B3 = {0.f, 0.f};

            #define PF(PA, PB, QA, QB, base) { \
                PA = swrow[(base) + g]; PB = swrow[(base) + 4 + g]; \
                QA = *(const uint4*)(hbp + (__float_as_int(PA.x) + j16)); \
                QB = *(const uint4*)(hbp + (__float_as_int(PB.x) + j16)); }
            #define CONSUME(PA, PB, QA, QB) { \
                v2f wA = {PA.y, PA.y}; \
                v2f wB = {PB.y, PB.y}; \
                v2f vA0 = {__uint_as_float(QA.x << 16), __uint_as_float(QA.x & 0xFFFF0000u)}; \
                v2f vA1 = {__uint_as_float(QA.y << 16), __uint_as_float(QA.y & 0xFFFF0000u)}; \
                v2f vA2 = {__uint_as_float(QA.z << 16), __uint_as_float(QA.z & 0xFFFF0000u)}; \
                v2f vA3 = {__uint_as_float(QA.w << 16), __uint_as_float(QA.w & 0xFFFF0000u)}; \
                A0 = __builtin_elementwise_fma(wA, vA0, A0); \
                A1 = __builtin_elementwise_fma(wA, vA1, A1); \
                A2 = __builtin_elementwise_fma(wA, vA2, A2); \
                A3 = __builtin_elementwise_fma(wA, vA3, A3); \
                v2f vB0 = {__uint_as_float(QB.x << 16), __uint_as_float(QB.x & 0xFFFF0000u)}; \
                v2f vB1 = {__uint_as_float(QB.y << 16), __uint_as_float(QB.y & 0xFFFF0000u)}; \
                v2f vB2 = {__uint_as_float(QB.z << 16), __uint_as_float(QB.z & 0xFFFF0000u)}; \
                v2f vB3 = {__uint_as_float(QB.w << 16), __uint_as_float(QB.w & 0xFFFF0000u)}; \
                B0 = __builtin_elementwise_fma(wB, vB0, B0); \
                B1 = __builtin_elementwise_fma(wB, vB1, B1); \
                B2 = __builtin_elementwise_fma(wB, vB2, B2); \
                B3 = __builtin_elementwise_fma(wB, vB3, B3); }

            float2 pA0, pB0, pA1, pB1, pA2, pB2;
            uint4 qA0, qB0, qA1, qB1, qA2, qB2;
            PF(pA0, pB0, qA0, qB0, 0)      // pair@0 (quads 0,1)
            PF(pA1, pB1, qA1, qB1, 8)      // pair@2 (quads 2,3)
            int i = 0;
            for (;;) {
                PF(pA2, pB2, qA2, qB2, 4 * i + 16)   // pair@(i+4)
                CONSUME(pA0, pB0, qA0, qB0)           // pair@i
                i += 2; if (i >= nit) break;
                PF(pA0, pB0, qA0, qB0, 4 * i + 16)
                CONSUME(pA1, pB1, qA1, qB1)
                i += 2; if (i >= nit) break;
                PF(pA1, pB1, qA1, qB1, 4 * i + 16)
                CONSUME(pA2, pB2, qA2, qB2)
                i += 2; if (i >= nit) break;
            }
            #undef PF
            #undef CONSUME

            A0 += B0; A1 += B1; A2 += B2; A3 += B3;
            float a0 = A0.x, a1 = A0.y, a2 = A1.x, a3 = A1.y;
            float a4 = A2.x, a5 = A2.y, a6 = A3.x, a7 = A3.y;
            #pragma unroll
            for (int o = 8; o <= 16; o <<= 1) {
                a0 += __shfl_xor(a0, o);
                a1 += __shfl_xor(a1, o);
                a2 += __shfl_xor(a2, o);
                a3 += __shfl_xor(a3, o);
                a4 += __shfl_xor(a4, o);
                a5 += __shfl_xor(a5, o);
                a6 += __shfl_xor(a6, o);
                a7 += __shfl_xor(a7, o);
            }
            float inv = 1.0f / (den + 1e-16f);
            if (sub < 16) {
                int jj = sub & 7;
                int half2 = sub >> 3;         // 0: feats 8jj+0..3, 1: feats 8jj+4..7
                float4 bv = ((const float4*)bias)[(jj << 1) | half2];
                float4 r;
                r.x = (half2 ? a4 : a0) * inv + bv.x;
                r.y = (half2 ? a5 : a1) * inv + bv.y;
                r.z = (half2 ? a6 : a2) * inv + bv.z;
                r.w = (half2 ? a7 : a3) * inv + bv.w;
                r.x = fmaxf(r.x, 0.f); r.y = fmaxf(r.y, 0.f);
                r.z = fmaxf(r.z, 0.f); r.w = fmaxf(r.w, 0.f);
                *(float4*)&xs[nl * 64 + jj * 8 + half2 * 4] = r;
            }
        } else {
            // slow path (deg>64, ~1e-18 prob): half-wave strided max, serial accumulate
            float m = -1e30f;
            for (int j = beg + sub; j < end; j += 32) {
                float e = es_in[csr_src[j]] + edn;
                e = e > 0.f ? e : 0.2f * e;
                m = fmaxf(m, e);
            }
            #pragma unroll
            for (int o = 16; o > 0; o >>= 1) m = fmaxf(m, __shfl_xor(m, o));
            float accL = 0.f, accH = 0.f, den = 0.f;
            for (int j = beg; j < end; ++j) {
                int s = csr_src[j];
                float e = es_in[s] + edn;
                e = e > 0.f ? e : 0.2f * e;
                float w = __expf(e - m);
                den += w;
                unsigned q = hb_in[(size_t)s * 32 + sub];
                accL = fmaf(w, __uint_as_float(q << 16), accL);
                accH = fmaf(w, __uint_as_float(q & 0xFFFF0000u), accH);
            }
            float inv = 1.0f / (den + 1e-16f);
            float2 b2v = ((const float2*)bias)[sub];
            float vL = accL * inv + b2v.x;
            float vH = accH * inv + b2v.y;
            vL = vL > 0.f ? vL : 0.f;
            vH = vH > 0.f ? vH : 0.f;
            ((float2*)&xs[nl * 64])[sub] = make_float2(vL, vH);
        }
    }
    __syncthreads();   // gather done: sw dead everywhere, xs complete

    // stage Ws over sw's region (FUSE only) — consumed after the next barrier
    if (FUSE) {
        int c = threadIdx.x & 63;
        int q0 = threadIdx.x >> 6;
        #pragma unroll
        for (int it = 0; it < 4; ++it) {
            int q = q0 + 4 * it;
            float4 v;
            v.x = Wn[(4 * q + 0) * F + c];
            v.y = Wn[(4 * q + 1) * F + c];
            v.z = Wn[(4 * q + 2) * F + c];
            v.w = Wn[(4 * q + 3) * F + c];
            *(float4*)&Ws[(q * 64 + c) * 4] = v;
        }
    }

    // fused mean-pool accumulation: wave 0, one feature per lane, run-reduce by graph
    if (threadIdx.x < 64) {
        int f = threadIdx.x;
        float s = 0.f;
        int gprev = gsh[0];
        for (int r = 0; r < nrows; ++r) {
            int g = gsh[r];
            if (g != gprev) {
                atomicAdd(&pooled[(size_t)gprev * 192 + segoff + f], s);
                s = 0.f; gprev = g;
            }
            s += xs[r * 64 + f];
        }
        atomicAdd(&pooled[(size_t)gprev * 192 + segoff + f], s);
    }

    if (FUSE) {
        __syncthreads();   // Ws visible to all waves
        float as_l = ans[lane];
        float ad_l = and_[lane];
        int r0 = wave, r1 = wave + 4;
        const float4* wv4 = (const float4*)Ws;
        const float4* x0v = (const float4*)&xs[r0 * 64];
        const float4* x1v = (const float4*)&xs[r1 * 64];
        float a0 = 0.f, a1 = 0.f, a2 = 0.f, a3 = 0.f;
        float b0 = 0.f, b1 = 0.f, b2 = 0.f, b3 = 0.f;
        #pragma unroll
        for (int k4 = 0; k4 < 16; ++k4) {
            float4 wv = wv4[k4 * 64 + lane];
            float4 xa = x0v[k4];
            float4 xb = x1v[k4];
            a0 = fmaf(xa.x, wv.x, a0);
            a1 = fmaf(xa.y, wv.y, a1);
            a2 = fmaf(xa.z, wv.z, a2);
            a3 = fmaf(xa.w, wv.w, a3);
            b0 = fmaf(xb.x, wv.x, b0);
            b1 = fmaf(xb.y, wv.y, b1);
            b2 = fmaf(xb.z, wv.z, b2);
            b3 = fmaf(xb.w, wv.w, b3);
        }
        float h0 = (a0 + a1) + (a2 + a3);
        float h1 = (b0 + b1) + (b2 + b3);
        float vs0 = h0 * as_l, vd0 = h0 * ad_l;
        float vs1 = h1 * as_l, vd1 = h1 * ad_l;
        #pragma unroll
        for (int o = 32; o > 0; o >>= 1) {
            vs0 += __shfl_down(vs0, o);
            vd0 += __shfl_down(vd0, o);
            vs1 += __shfl_down(vs1, o);
            vd1 += __shfl_down(vd1, o);
        }
        int nd0 = base8 + r0, nd1 = base8 + r1;
        if (lane == 0) {
            if (nd0 < N) { es_out[nd0] = vs0; ed_out[nd0] = vd0; }
            if (nd1 < N) { es_out[nd1] = vs1; ed_out[nd1] = vd1; }
        }
        unsigned u0 = __float_as_uint(h0);
        unsigned rb0 = (u0 + 0x7FFF + ((u0 >> 16) & 1)) >> 16;
        unsigned pb0 = (unsigned)__shfl_xor((int)rb0, 1);
        unsigned u1 = __float_as_uint(h1);
        unsigned rb1 = (u1 + 0x7FFF + ((u1 >> 16) & 1)) >> 16;
        unsigned pb1 = (unsigned)__shfl_xor((int)rb1, 1);
        if ((lane & 1) == 0) {
            if (nd0 < N) hb_out[(size_t)nd0 * 32 + (lane >> 1)] = (pb0 << 16) | rb0;
            if (nd1 < N) hb_out[(size_t)nd1 * 32 + (lane >> 1)] = (pb1 << 16) | rb1;
        }
    }
}

// ---------------- final linear + softmax ----------------
__global__ void head_kernel(const float* __restrict__ pooled, const int* __restrict__ gstart,
                            const float* __restrict__ Wo, const float* __restrict__ bo,
                            float* __restrict__ out) {
    int g = blockIdx.x * blockDim.x + threadIdx.x;
    if (g >= GRAPHS) return;
    int cntg = gstart[g + 1] - gstart[g];
    float inv = 1.0f / fmaxf((float)cntg, 1.0f);
    float acc[CLASSES];
    #pragma unroll
    for (int c = 0; c < CLASSES; ++c) acc[c] = bo[c];
    for (int f = 0; f < 192; ++f) {
        float p = pooled[g * 192 + f] * inv;
        #pragma unroll
        for (int c = 0; c < CLASSES; ++c) acc[c] = fmaf(p, Wo[f * CLASSES + c], acc[c]);
    }
    float mx = acc[0];
    #pragma unroll
    for (int c = 1; c < CLASSES; ++c) mx = fmaxf(mx, acc[c]);
    float s = 0.f;
    #pragma unroll
    for (int c = 0; c < CLASSES; ++c) { acc[c] = __expf(acc[c] - mx); s += acc[c]; }
    float invs = 1.0f / s;
    #pragma unroll
    for (int c = 0; c < CLASSES; ++c) out[g * CLASSES + c] = acc[c] * invs;
}

extern "C" void kernel_launch(void* const* d_in, const int* in_sizes, int n_in,
                              void* d_out, int out_size, void* d_ws, size_t ws_size,
                              hipStream_t stream) {
    const float* x   = (const float*)d_in[0];
    const int* ei    = (const int*)d_in[1];
    const int* batch = (const int*)d_in[2];
    const float* W1  = (const float*)d_in[3];
    const float* a1s = (const float*)d_in[4];
    const float* a1d = (const float*)d_in[5];
    const float* b1  = (const float*)d_in[6];
    const float* W2  = (const float*)d_in[7];
    const float* a2s = (const float*)d_in[8];
    const float* a2d = (const float*)d_in[9];
    const float* b2  = (const float*)d_in[10];
    const float* W3  = (const float*)d_in[11];
    const float* a3s = (const float*)d_in[12];
    const float* a3d = (const float*)d_in[13];
    const float* b3  = (const float*)d_in[14];
    const float* Wo  = (const float*)d_in[15];
    const float* bo  = (const float*)d_in[16];
    float* out = (float*)d_out;

    const int N = in_sizes[2];
    const int E = in_sizes[1] / 2;
    const int TOT = E + N;
    const int NB = (N + 255) >> 8;
    const int M  = NB * NBLK;

    char* p = (char*)d_ws;
    auto alloc = [&](size_t bytes) { char* r = p; p += (bytes + 255) & ~(size_t)255; return r; };
    unsigned* hbA  = (unsigned*)alloc((size_t)N * 32 * 4);
    unsigned* hbB  = (unsigned*)alloc((size_t)N * 32 * 4);
    float* esA     = (float*)alloc((size_t)N * 4);
    float* edA     = (float*)alloc((size_t)N * 4);
    float* esB     = (float*)alloc((size_t)N * 4);
    float* edB     = (float*)alloc((size_t)N * 4);
    int* rowptr    = (int*)alloc((size_t)(N + 1) * 4);
    int* csr_src   = (int*)alloc((size_t)TOT * 4);
    unsigned* stage= (unsigned*)alloc((size_t)E * 4);
    int* hist      = (int*)alloc((size_t)M * 4);
    int* shist     = (int*)alloc((size_t)M * 4);
    int* partial   = (int*)alloc((size_t)SCAN_T * 4);
    float* pooled  = (float*)alloc((size_t)GRAPHS * 192 * 4);
    int* gstart    = (int*)alloc((size_t)(GRAPHS + 1) * 4);

    hipMemsetAsync(pooled, 0, (size_t)GRAPHS * 192 * 4, stream);

    const int GB = (N + 63) / 64;
    const size_t SMG = 40960;                                  // Wf (32KB) + hs (8KB)
    const size_t SMF  = (size_t)4096 * 4 + 2048;               // Ws(=sw overlay 16K) + xs = 18.4KB
    const size_t SMNF = 6144 + 2048;                           // sw(8x96) + xs
    int agg_blocks = (N + 7) / 8;
    int scan_blocks = M / 256;                                 // = NB (<= 1024)

    // fused layer-1 GEMM + dst-histogram + graph-bounds (independent work, one launch)
    gemm_hist<<<GB + NBLK + 3, 256, SMG, stream>>>(x, W1, a1s, a1d, hbA, esA, edA, N, GB,
                                                   ei, E, NB, hist, batch, gstart);
    // parallel 3-phase exclusive scan
    scan_p1<<<scan_blocks, 256, 0, stream>>>(hist, partial);
    scan_p2<<<1, SCAN_T, 0, stream>>>(partial, scan_blocks);
    scan_p3<<<scan_blocks, 256, 0, stream>>>(hist, partial, shist);
    scatter3<<<NBLK, 256, 0, stream>>>(ei, E, NB, shist, stage);
    place2<<<NB, 256, 0, stream>>>(stage, shist, rowptr, csr_src, N, E, NB);

    // agg1 (+pool seg0) + fused gemm2
    gat_agg_fused<true><<<agg_blocks, 256, SMF, stream>>>(hbA, esA, edA, rowptr, csr_src, b1,
                                                          W2, a2s, a2d, batch, 0, pooled,
                                                          hbB, esB, edB, N);
    // agg2 (+pool seg1) + fused gemm3
    gat_agg_fused<true><<<agg_blocks, 256, SMF, stream>>>(hbB, esB, edB, rowptr, csr_src, b2,
                                                          W3, a3s, a3d, batch, 64, pooled,
                                                          hbA, esA, edA, N);
    // agg3 (+pool seg2, no fusion)
    gat_agg_fused<false><<<agg_blocks, 256, SMNF, stream>>>(hbA, esA, edA, rowptr, csr_src, b3,
                                                            nullptr, nullptr, nullptr,
                                                            batch, 128, pooled,
                                                            nullptr, nullptr, nullptr, N);

    // readout
    head_kernel<<<(GRAPHS + 255) / 256, 256, 0, stream>>>(pooled, gstart, Wo, bo, out);
}